// Round 14
// baseline (607.619 us; speedup 1.0000x reference)
//
#include <hip/hip_runtime.h>

typedef unsigned short u16;
typedef __attribute__((ext_vector_type(8))) short short8;
typedef __attribute__((ext_vector_type(4))) float f32x4;

#define Bn 4096
#define Vn 20
#define Dn 768
#define Mn (Bn * Vn)   // 81920 rows
#define Nn (2 * Dn)    // 1536 packed m1/m2 columns

#define BM 256
#define BNt 128            // Wt rows per block tile (= 64 output e-columns)
#define HK 32              // K per slice
#define NHK (Dn / HK)      // 24 slices
#define NTILES (Nn / BNt)  // 12 N-tiles
#define GRID ((Mn / BM) * NTILES)   // 320 * 12 = 3840, %8 == 0
#define SLOTU 8192         // u16 per slot: A 256x32 ONLY (B is in registers)

typedef __attribute__((address_space(1))) void GV;
typedef __attribute__((address_space(3))) void LV;

__device__ __forceinline__ u16 f2bf(float f) {
  union { float f; unsigned u; } v; v.f = f;
  unsigned r = v.u + 0x7FFFu + ((v.u >> 16) & 1u);  // round-to-nearest-even
  return (u16)(r >> 16);
}
__device__ __forceinline__ float bf2f(u16 x) {
  union { unsigned u; float f; } v; v.u = ((unsigned)x) << 16; return v.f;
}

// A LDS map within a 256x32 (rows x K) u16 slot (proven 0-conflict R6-R13):
//   idx = (r>>1)*64 + (r&1)*32 + ((kc ^ ((r>>1)&3))*8) + j
__device__ __forceinline__ int lds_off(int r, int hi) {
  return (r >> 1) * 64 + (r & 1) * 32 + ((hi ^ ((r >> 1) & 3)) * 8);
}
// conv-epilogue LDS map: [c][r] col-major with row-XOR swizzle
__device__ __forceinline__ int fsw(int c, int r) {
  return c * 256 + (r ^ ((c & 31) << 3));
}

// ---------------- kernel 1: row softmax -> bf16 X (row-major) ---------------
__global__ __launch_bounds__(192) void softmax_k(const float* __restrict__ vf,
                                                 u16* __restrict__ X) {
  size_t row = blockIdx.x;
  const float4* p = (const float4*)(vf + row * Dn);
  int t = threadIdx.x;
  float4 v = p[t];
  float mx = fmaxf(fmaxf(v.x, v.y), fmaxf(v.z, v.w));
  #pragma unroll
  for (int off = 32; off; off >>= 1) mx = fmaxf(mx, __shfl_xor(mx, off));
  __shared__ float rr[3];
  __shared__ float rs[3];
  int wv = t >> 6, ln = t & 63;
  if (!ln) rr[wv] = mx;
  __syncthreads();
  mx = fmaxf(fmaxf(rr[0], rr[1]), rr[2]);
  float e0 = __expf(v.x - mx), e1 = __expf(v.y - mx);
  float e2 = __expf(v.z - mx), e3 = __expf(v.w - mx);
  float s = e0 + e1 + e2 + e3;
  #pragma unroll
  for (int off = 32; off; off >>= 1) s += __shfl_xor(s, off);
  if (!ln) rs[wv] = s;
  __syncthreads();
  float inv = 1.0f / (rs[0] + rs[1] + rs[2]);
  ushort4 o;
  o.x = f2bf(e0 * inv); o.y = f2bf(e1 * inv);
  o.z = f2bf(e2 * inv); o.w = f2bf(e3 * inv);
  ((ushort4*)(X + row * Dn))[t] = o;
}

// ------- kernel 2: pack W1/W2 block-of-32 interleaved, bf16 [1536][768] -----
__global__ __launch_bounds__(256) void build_wt_k(const float* __restrict__ W1,
                                                  const float* __restrict__ W2,
                                                  u16* __restrict__ Wt) {
  int idx = blockIdx.x * 256 + threadIdx.x;
  if (idx >= Dn * Dn) return;
  int j = idx / Dn, d = idx - j * Dn;
  int b = j >> 5, c = j & 31;
  Wt[(size_t)(b * 64 + c) * Dn + d]      = f2bf(W1[(size_t)j * Dn + d]);
  Wt[(size_t)(b * 64 + 32 + c) * Dn + d] = f2bf(W2[(size_t)j * Dn + d]);
}

// -------- kernel 3: GEMM, A-only LDS + B direct global->VGPR (L2-warm) ------
// 8 waves (4M x 2N), wave tile 64x64, 24 K32-slices, 2-slot A ring (32 KiB).
// B (Wt, 2.25 MB, L2-resident) is loaded per-wave straight to registers,
// double-buffered Bcur/Bnxt, prefetched 1 slice ahead — halves LDS traffic
// (the serial-sum bottleneck pipe) and moves B's wave-duplication to L2.
// Ledger (issue order ...SA(s)@end(s-2), LB(s)@s-1, SA(s+1)@end(s-1)):
//   top-of-slice wait = vmcnt(2)  [A lead 1.5 slices > HBM 900cy; B lead 1
//   slice >> L2 200cy]; WAR barrier before SA (R12 lesson); tail vmcnt(0).
__global__ __launch_bounds__(512, 4) void gemm_fuse_k(
    const u16* __restrict__ X, const u16* __restrict__ Wt,
    const float* __restrict__ b1, const float* __restrict__ b2,
    const float* __restrict__ text, float* __restrict__ out,
    u16* __restrict__ seam,
    const float* __restrict__ cw1, const float* __restrict__ cb1,
    const float* __restrict__ cw2, const float* __restrict__ cb2) {
  __shared__ __align__(16) u16 smem[32768];   // 64 KiB (loop uses 32 KiB)

  const int h = blockIdx.x;                      // GRID = 3840, %8==0
  const int lin = (h & 7) * (GRID / 8) + (h >> 3);
  const int by = lin / NTILES, bx = lin - by * NTILES;
  const int brow = by * BM;

  const int t = threadIdx.x, w = t >> 6, l = t & 63;
  const int lo = l & 15, hi = l >> 4;
  const int wrr = w >> 1, wcc = w & 1;           // 4M x 2N

  int offA[4];
  #pragma unroll
  for (int m = 0; m < 4; ++m) offA[m] = lds_off(wrr * 64 + m * 16 + lo, hi);

  // A staging sources: thread q fills u16 [q*8..q*8+8) of the 256x32 region
  const u16* gA[2];
  #pragma unroll
  for (int ii = 0; ii < 2; ++ii) {
    int q = ii * 512 + t;
    int rp = q >> 3, half = (q >> 2) & 1, kc = (q & 3) ^ (rp & 3);
    gA[ii] = X + (size_t)(brow + rp * 2 + half) * Dn + kc * 8;
  }
  // B per-lane register-load base: row = bx*128 + wcc*64 + n*16 + lo,
  // k-offset = s*32 + hi*8  (matches the verified LDS-path fragment content)
  const u16* bbase = Wt + (size_t)(bx * BNt + wcc * 64 + lo) * Dn + hi * 8;

#define SA(SLOT, KOFF) do { _Pragma("unroll")                                  \
    for (int ii = 0; ii < 2; ++ii)                                             \
      __builtin_amdgcn_global_load_lds((GV*)(gA[ii] + (KOFF)),                 \
          (LV*)(smem + (SLOT) * SLOTU + (ii * 512 + t) * 8), 16, 0, 0);        \
  } while (0)
#define LB(SET, S) do { _Pragma("unroll") for (int n = 0; n < 4; ++n)          \
    SET[n] = *(const short8*)(bbase + (size_t)n * 16 * Dn + (S) * HK);         \
  } while (0)

  short8 Bcur[4], Bnxt[4];
  // prologue (issue order matters for the vmcnt ledger): SA0, LB0, SA1
  SA(0, 0);
  LB(Bcur, 0);
  SA(1, HK);

  f32x4 acc[4][4] = {};
  short8 af[4];

#define BODY(S, BU, BL, DO_LB, DO_SA, VMN) do {                                \
    asm volatile("s_waitcnt vmcnt(" #VMN ")" ::: "memory");                    \
    __builtin_amdgcn_s_barrier();                                              \
    { const u16* sa_ = smem + ((S) & 1) * SLOTU;                               \
      _Pragma("unroll") for (int m = 0; m < 4; ++m)                            \
        af[m] = *(const short8*)(sa_ + offA[m]); }                             \
    if (DO_LB) LB(BL, (S) + 1);                                                \
    asm volatile("s_waitcnt lgkmcnt(0)" ::: "memory");                         \
    __builtin_amdgcn_sched_barrier(0);                                         \
    __builtin_amdgcn_s_setprio(1);                                             \
    _Pragma("unroll") for (int m = 0; m < 4; ++m) {                            \
      acc[m][0] = __builtin_amdgcn_mfma_f32_16x16x32_bf16(af[m], BU[0], acc[m][0], 0, 0, 0); \
      acc[m][1] = __builtin_amdgcn_mfma_f32_16x16x32_bf16(af[m], BU[1], acc[m][1], 0, 0, 0); \
      acc[m][2] = __builtin_amdgcn_mfma_f32_16x16x32_bf16(af[m], BU[2], acc[m][2], 0, 0, 0); \
      acc[m][3] = __builtin_amdgcn_mfma_f32_16x16x32_bf16(af[m], BU[3], acc[m][3], 0, 0, 0); \
    }                                                                          \
    __builtin_amdgcn_s_setprio(0);                                             \
    __builtin_amdgcn_s_barrier();   /* WAR guard before slot overwrite */      \
    if (DO_SA) SA((S) & 1, ((S) + 2) * HK);                                    \
  } while (0)

  // steady state: slices 0..21 (all guards true), even->Bcur, odd->Bnxt
  for (int sp = 0; sp < 11; ++sp) {
    const int s0 = 2 * sp, s1 = 2 * sp + 1;
    BODY(s0, Bcur, Bnxt, true, true, 2);
    BODY(s1, Bnxt, Bcur, true, true, 2);
  }
  // tail: slice 22 (stage nothing, still prefetch B23), slice 23 (drain)
  BODY(22, Bcur, Bnxt, true,  false, 2);
  BODY(23, Bnxt, Bcur, false, false, 0);
#undef BODY
#undef SA
#undef LB

  __syncthreads();   // all slot-reads done before LDS reuse by epilogue

  // ======================= fused-conv epilogue ==============================
  const float w10 = cw1[0], w11 = cw1[1], w12 = cw1[2], c1b = cb1[0];
  const float w20 = cw2[0], w21 = cw2[1], w22 = cw2[2], c2b = cb2[0];

  u16* fsm = smem;           // fused [64 c][256 r], swizzled: 32 KiB
  u16* tsm = smem + 16384;   // tmp, same layout: 32 KiB

  // ---- E1: fused -> LDS bf16 (+ seam store for cols 0-3, 60-63) ----
  #pragma unroll
  for (int n = 0; n < 2; ++n) {
    const int cl = wcc * 32 + n * 16 + lo;       // local col 0..63
    const int e  = bx * 64 + cl;
    const float B1 = b1[e], B2 = b2[e];
    #pragma unroll
    for (int m = 0; m < 4; ++m) {
      const int rl = wrr * 64 + m * 16 + hi * 4;
      uint2 pk;
      u16* pku = (u16*)&pk;
      #pragma unroll
      for (int r = 0; r < 4; ++r) {
        const int gr = brow + rl + r;
        const float v1 = acc[m][n][r] + B1;
        const float v2 = acc[m][n + 2][r] + B2;
        const float tf = text[(size_t)(gr / Vn) * Dn + e];
        pku[r] = f2bf(fmaxf(tf * v1 + v2, 0.0f));
      }
      *(uint2*)(fsm + fsw(cl, rl)) = pk;
      const int sidx = (cl < 4) ? cl : ((cl >= 60) ? cl - 56 : -1);
      if (sidx >= 0)
        *(uint2*)(seam + ((size_t)(by * NTILES + bx) * 8 + sidx) * 256 + rl) = pk;
    }
  }
  __syncthreads();

  // ---- E2: tmp = relu(conv1(fused)); own col kept in regs ----
  const int cl = t & 63, rb = t >> 6;            // 8 row-groups of 32
  const int cL = cl ? cl - 1 : 0, cR = (cl < 63) ? cl + 1 : 63;
  short8 tC[4];
  #pragma unroll
  for (int j = 0; j < 4; ++j) {
    const int R = rb * 32 + j * 8;
    short8 sL = *(const short8*)(fsm + fsw(cL, R));
    short8 sC = *(const short8*)(fsm + fsw(cl, R));
    short8 sR = *(const short8*)(fsm + fsw(cR, R));
    short8 o;
    #pragma unroll
    for (int k = 0; k < 8; ++k) {
      float a = bf2f((u16)sL[k]), b = bf2f((u16)sC[k]), c = bf2f((u16)sR[k]);
      o[k] = (short)f2bf(fmaxf(fmaf(w10, a, fmaf(w11, b, fmaf(w12, c, c1b))), 0.0f));
    }
    *(short8*)(tsm + fsw(cl, R)) = o;
    tC[j] = o;
  }
  __syncthreads();

  // ---- E3: out = conv2(tmp), store interior cols 2..61 ----
  const bool wr_ok = (cl >= 2 && cl <= 61);
  #pragma unroll
  for (int j = 0; j < 4; ++j) {
    const int R = rb * 32 + j * 8;
    short8 tL = *(const short8*)(tsm + fsw(cL, R));
    short8 tR = *(const short8*)(tsm + fsw(cR, R));
    #pragma unroll
    for (int k = 0; k < 8; ++k) {
      float v = fmaf(w20, bf2f((u16)tL[k]),
                fmaf(w21, bf2f((u16)tC[j][k]),
                fmaf(w22, bf2f((u16)tR[k]), c2b)));
      if (wr_ok)
        out[(size_t)(brow + R + k) * Dn + bx * 64 + cl] = v;
    }
  }
}

// ------- kernel 4: seam cleanup — out cols {E0,E0+1,E0+62,E0+63} -----------
__global__ __launch_bounds__(256) void seam_k(const u16* __restrict__ seam,
                                              float* __restrict__ out,
                                              const float* __restrict__ cw1,
                                              const float* __restrict__ cb1,
                                              const float* __restrict__ cw2,
                                              const float* __restrict__ cb2) {
  const int bid = blockIdx.x;          // by*12+bx
  const int by = bid / NTILES, bx = bid - by * NTILES;
  const int r = threadIdx.x;
  const float w10 = cw1[0], w11 = cw1[1], w12 = cw1[2], c1b = cb1[0];
  const float w20 = cw2[0], w21 = cw2[1], w22 = cw2[2], c2b = cb2[0];
  #define SM(B, I) bf2f(seam[((size_t)(B) * 8 + (I)) * 256 + r])
  float fm2 = 0.f, fm1 = 0.f, fR0 = 0.f, fR1 = 0.f;
  if (bx > 0)          { fm2 = SM(bid - 1, 6); fm1 = SM(bid - 1, 7); }
  if (bx < NTILES - 1) { fR0 = SM(bid + 1, 0); fR1 = SM(bid + 1, 1); }
  const float f0 = SM(bid, 0), f1 = SM(bid, 1), f2 = SM(bid, 2), f3 = SM(bid, 3);
  const float f60 = SM(bid, 4), f61 = SM(bid, 5), f62 = SM(bid, 6), f63 = SM(bid, 7);
  #undef SM
  #define C1(a, b, c) fmaxf(fmaf(w10, (a), fmaf(w11, (b), fmaf(w12, (c), c1b))), 0.0f)
  const float tm1 = (bx > 0) ? C1(fm2, fm1, f0) : 0.0f;
  const float t0  = C1(fm1, f0, f1);
  const float t1  = C1(f0, f1, f2);
  const float t2  = C1(f1, f2, f3);
  const float t61 = C1(f60, f61, f62);
  const float t62 = C1(f61, f62, f63);
  const float t63 = C1(f62, f63, fR0);
  const float t64 = (bx < NTILES - 1) ? C1(f63, fR0, fR1) : 0.0f;
  #undef C1
  const size_t go = (size_t)(by * 256 + r) * Dn + bx * 64;
  out[go + 0]  = fmaf(w20, tm1, fmaf(w21, t0,  fmaf(w22, t1,  c2b)));
  out[go + 1]  = fmaf(w20, t0,  fmaf(w21, t1,  fmaf(w22, t2,  c2b)));
  out[go + 62] = fmaf(w20, t61, fmaf(w21, t62, fmaf(w22, t63, c2b)));
  out[go + 63] = fmaf(w20, t62, fmaf(w21, t63, fmaf(w22, t64, c2b)));
}

extern "C" void kernel_launch(void* const* d_in, const int* in_sizes, int n_in,
                              void* d_out, int out_size, void* d_ws, size_t ws_size,
                              hipStream_t stream) {
  const float* text = (const float*)d_in[0];
  const float* vf   = (const float*)d_in[1];
  const float* W1   = (const float*)d_in[2];
  const float* b1   = (const float*)d_in[3];
  const float* W2   = (const float*)d_in[4];
  const float* b2   = (const float*)d_in[5];
  const float* cw1  = (const float*)d_in[6];
  const float* cb1  = (const float*)d_in[7];
  const float* cw2  = (const float*)d_in[8];
  const float* cb2  = (const float*)d_in[9];
  float* out = (float*)d_out;

  u16* X    = (u16*)d_ws;                        // [81920][768] bf16
  u16* Wt   = X + (size_t)Mn * Dn;               // [1536][768] bf16
  u16* seam = Wt + (size_t)Nn * Dn;              // [3840][8][256] bf16

  softmax_k<<<Mn, 192, 0, stream>>>(vf, X);
  build_wt_k<<<(Dn * Dn + 255) / 256, 256, 0, stream>>>(W1, W2, Wt);
  gemm_fuse_k<<<GRID, 512, 0, stream>>>(X, Wt, b1, b2, text, out, seam,
                                        cw1, cb1, cw2, cb2);
  seam_k<<<GRID, 256, 0, stream>>>(seam, out, cw1, cb1, cw2, cb2);
}

// Round 15
// 373.022 us; speedup vs baseline: 1.6289x; 1.6289x over previous
//
#include <hip/hip_runtime.h>

typedef unsigned short u16;
typedef __attribute__((ext_vector_type(8))) short short8;
typedef __attribute__((ext_vector_type(4))) float f32x4;

#define Bn 4096
#define Vn 20
#define Dn 768
#define Mn (Bn * Vn)   // 81920 rows
#define Nn (2 * Dn)    // 1536 packed m1/m2 columns

#define BM 256
#define BNt 256            // Wt rows per block tile (= 128 output e-columns)
#define NTILES (Nn / BNt)  // 6 N-tiles
#define GRID ((Mn / BM) * NTILES)   // 320 * 6 = 1920, %8 == 0

typedef __attribute__((address_space(1))) void GV;
typedef __attribute__((address_space(3))) void LV;

__device__ __forceinline__ u16 f2bf(float f) {
  union { float f; unsigned u; } v; v.f = f;
  unsigned r = v.u + 0x7FFFu + ((v.u >> 16) & 1u);  // round-to-nearest-even
  return (u16)(r >> 16);
}
__device__ __forceinline__ float bf2f(u16 x) {
  union { unsigned u; float f; } v; v.u = ((unsigned)x) << 16; return v.f;
}

// LDS layout within a 256x32 (rows x K) u16 region (K-loop staging):
//   u16 index = (r>>1)*64 + (r&1)*32 + ((kc ^ ((r>>1)&3))*8) + j
__device__ __forceinline__ int lds_off(int r, int hi) {
  return (r >> 1) * 64 + (r & 1) * 32 + ((hi ^ ((r >> 1) & 3)) * 8);
}

// ---------------- kernel 1: row softmax -> bf16 X ----------------
__global__ __launch_bounds__(192) void softmax_k(const float* __restrict__ vf,
                                                 u16* __restrict__ X) {
  size_t row = blockIdx.x;
  const float4* p = (const float4*)(vf + row * Dn);
  int t = threadIdx.x;
  float4 v = p[t];
  float mx = fmaxf(fmaxf(v.x, v.y), fmaxf(v.z, v.w));
  #pragma unroll
  for (int off = 32; off; off >>= 1) mx = fmaxf(mx, __shfl_xor(mx, off));
  __shared__ float rr[3];
  __shared__ float rs[3];
  int wv = t >> 6, ln = t & 63;
  if (!ln) rr[wv] = mx;
  __syncthreads();
  mx = fmaxf(fmaxf(rr[0], rr[1]), rr[2]);
  float e0 = __expf(v.x - mx), e1 = __expf(v.y - mx);
  float e2 = __expf(v.z - mx), e3 = __expf(v.w - mx);
  float s = e0 + e1 + e2 + e3;
  #pragma unroll
  for (int off = 32; off; off >>= 1) s += __shfl_xor(s, off);
  if (!ln) rs[wv] = s;
  __syncthreads();
  float inv = 1.0f / (rs[0] + rs[1] + rs[2]);
  ushort4 o;
  o.x = f2bf(e0 * inv); o.y = f2bf(e1 * inv);
  o.z = f2bf(e2 * inv); o.w = f2bf(e3 * inv);
  ((ushort4*)(X + row * Dn))[t] = o;
}

// ------- kernel 2: pack W1/W2 block-of-32 interleaved, bf16 [1536][768] -----
__global__ __launch_bounds__(256) void build_wt_k(const float* __restrict__ W1,
                                                  const float* __restrict__ W2,
                                                  u16* __restrict__ Wt) {
  int idx = blockIdx.x * 256 + threadIdx.x;
  if (idx >= Dn * Dn) return;
  int j = idx / Dn, d = idx - j * Dn;
  int b = j >> 5, c = j & 31;
  Wt[(size_t)(b * 64 + c) * Dn + d]      = f2bf(W1[(size_t)j * Dn + d]);
  Wt[(size_t)(b * 64 + 32 + c) * Dn + d] = f2bf(W2[(size_t)j * Dn + d]);
}

// -------- kernel 3: GEMM (R8 8-phase core) + FUSED CONV epilogue ------------
// After the K-loop the 128 KiB LDS is dead: stage fused=relu(text*m1+m2) as
// bf16 col-major [128 cols][256 rows] (XOR swizzle r^=(c&31)<<3), conv1->relu
// (E2) and conv2->store (E3) in-block for out cols 2..125; seam cols
// {0..3,124..127} stored to ws for seam_k.
__global__ __launch_bounds__(512, 2) void gemm_fuse_k(
    const u16* __restrict__ X, const u16* __restrict__ Wt,
    const float* __restrict__ b1, const float* __restrict__ b2,
    const float* __restrict__ text, float* __restrict__ out,
    u16* __restrict__ seam,
    const float* __restrict__ cw1, const float* __restrict__ cb1,
    const float* __restrict__ cw2, const float* __restrict__ cb2) {
  __shared__ __align__(16) u16 smem[65536];   // 128 KiB

  const int h = blockIdx.x;                      // GRID = 1920 blocks, %8==0
  const int lin = (h & 7) * (GRID / 8) + (h >> 3);
  const int by = lin / NTILES, bx = lin - by * NTILES;
  const int brow = by * BM;

  const int t = threadIdx.x, w = t >> 6, l = t & 63;
  const int lo = l & 15, hi = l >> 4;
  const int wrr = w >> 2, wcc = w & 3;

  int offA[8], offB[4];
  #pragma unroll
  for (int m = 0; m < 8; ++m) offA[m] = lds_off(wrr * 128 + m * 16 + lo, hi);
  #pragma unroll
  for (int n = 0; n < 4; ++n) offB[n] = lds_off(wcc * 64 + n * 16 + lo, hi);

  const u16* gA[2];
  const u16* gB[2];
  #pragma unroll
  for (int ii = 0; ii < 2; ++ii) {
    int q = ii * 512 + t;
    int rp = q >> 3, half = (q >> 2) & 1, kc = (q & 3) ^ (rp & 3);
    gA[ii] = X + (size_t)(brow + rp * 2 + half) * Dn + kc * 8;
    gB[ii] = Wt + (size_t)(bx * BNt + rp * 2 + half) * Dn + kc * 8;
  }

#define STG_A(DST, KOFF) do { _Pragma("unroll")                                \
    for (int ii = 0; ii < 2; ++ii)                                             \
      __builtin_amdgcn_global_load_lds((GV*)(gA[ii] + (KOFF)),                 \
          (LV*)(smem + (DST) + (ii * 512 + w * 64) * 8), 16, 0, 0); } while (0)
#define STG_B(DST, KOFF) do { _Pragma("unroll")                                \
    for (int ii = 0; ii < 2; ++ii)                                             \
      __builtin_amdgcn_global_load_lds((GV*)(gB[ii] + (KOFF)),                 \
          (LV*)(smem + (DST) + (ii * 512 + w * 64) * 8), 16, 0, 0); } while (0)

  STG_A(0, 0);              STG_B(16384, 0);          // T0 Kh0 -> slot0
  STG_A(32768, 64);         STG_B(49152, 64);         // T1 Kh0 -> slot1
  STG_A(8192, 32);          STG_B(24576, 32);         // T0 Kh1
  STG_A(40960, 96);         STG_B(57344, 96);         // T1 Kh1
  asm volatile("s_waitcnt vmcnt(12)" ::: "memory");   // T0-Kh0 resident
  __builtin_amdgcn_s_barrier();

  f32x4 acc[8][4] = {};
  short8 af[8], bb0, bb1;

#define PH(SB, KH, NH, NEWA, STG, VM) do {                                     \
    if (NEWA) { _Pragma("unroll") for (int m = 0; m < 8; ++m)                  \
      af[m] = *(const short8*)(smem + (SB) + (KH) * 8192 + offA[m]); }         \
    bb0 = *(const short8*)(smem + (SB) + 16384 + (KH) * 8192 + offB[(NH)*2]);  \
    bb1 = *(const short8*)(smem + (SB) + 16384 + (KH) * 8192 + offB[(NH)*2+1]);\
    STG;                                                                       \
    __builtin_amdgcn_s_barrier();                                              \
    asm volatile("s_waitcnt lgkmcnt(0)" ::: "memory");                         \
    __builtin_amdgcn_sched_barrier(0);                                         \
    __builtin_amdgcn_s_setprio(1);                                             \
    _Pragma("unroll") for (int m = 0; m < 8; ++m) {                            \
      acc[m][(NH)*2]   = __builtin_amdgcn_mfma_f32_16x16x32_bf16(af[m], bb0, acc[m][(NH)*2],   0, 0, 0); \
      acc[m][(NH)*2+1] = __builtin_amdgcn_mfma_f32_16x16x32_bf16(af[m], bb1, acc[m][(NH)*2+1], 0, 0, 0); \
    }                                                                          \
    __builtin_amdgcn_s_setprio(0);                                             \
    VM;                                                                        \
    __builtin_amdgcn_s_barrier();                                              \
  } while (0)

#define VM4 asm volatile("s_waitcnt vmcnt(4)" ::: "memory")
#define VM0 asm volatile("s_waitcnt vmcnt(0)" ::: "memory")

  #pragma unroll
  for (int i = 0; i < 6; ++i) {
    const int ka = (2 * i + 1) * 64;
    const int kb = (2 * i + 2) * 64;
    PH(0, 0, 0, true,  if (i >= 1) STG_A(32768, ka),      ;  );
    PH(0, 0, 1, false, if (i >= 1) STG_B(49152, ka),      VM4);
    PH(0, 1, 0, true,  if (i >= 1) STG_A(40960, ka + 32), ;  );
    PH(0, 1, 1, false, if (i >= 1) STG_B(57344, ka + 32), VM4);
    PH(32768, 0, 0, true,  if (i <= 4) STG_A(0, kb),          ;  );
    PH(32768, 0, 1, false, if (i <= 4) STG_B(16384, kb),      if (i == 5) { VM0; } else { VM4; });
    PH(32768, 1, 0, true,  if (i <= 4) STG_A(8192, kb + 32),  ;  );
    PH(32768, 1, 1, false, if (i <= 4) STG_B(24576, kb + 32), if (i <= 4) { VM4; });
  }
#undef PH
#undef VM4
#undef VM0
#undef STG_A
#undef STG_B

  // ======================= fused-conv epilogue ==============================
  // vmcnt==0 here (i=5 P6 drained; P7/P8 stage nothing) -> smem reusable.
  const float w10 = cw1[0], w11 = cw1[1], w12 = cw1[2], c1b = cb1[0];
  const float w20 = cw2[0], w21 = cw2[1], w22 = cw2[2], c2b = cb2[0];

  u16* fsm = smem;           // fused [c][r]: idx = c*256 + (r ^ ((c&31)<<3))
  u16* tsm = smem + 32768;   // tmp, same layout

  // ---- E1: fused -> LDS bf16 (+ seam store for cols 0-3,124-127) ----
  #pragma unroll
  for (int n = 0; n < 2; ++n) {
    const int cl = wcc * 32 + n * 16 + lo;       // local col 0..127
    const int e  = bx * 128 + cl;
    const float B1 = b1[e], B2 = b2[e];
    #pragma unroll
    for (int m = 0; m < 8; ++m) {
      const int rl = wrr * 128 + m * 16 + hi * 4;
      uint2 pk;
      u16* pku = (u16*)&pk;
      #pragma unroll
      for (int r = 0; r < 4; ++r) {
        const int gr = brow + rl + r;
        const float v1 = acc[m][n][r] + B1;
        const float v2 = acc[m][n + 2][r] + B2;
        const float tf = text[(size_t)(gr / Vn) * Dn + e];
        pku[r] = f2bf(fmaxf(tf * v1 + v2, 0.0f));
      }
      *(uint2*)(fsm + cl * 256 + (rl ^ ((cl & 31) << 3))) = pk;
      const int sidx = (cl < 4) ? cl : ((cl >= 124) ? cl - 120 : -1);
      if (sidx >= 0)
        *(uint2*)(seam + ((size_t)(by * 6 + bx) * 8 + sidx) * 256 + rl) = pk;
    }
  }
  __syncthreads();

  // ---- E2: tmp = relu(conv1(fused)), per-thread col; own col kept in regs --
  const int cl = t & 127, rb = t >> 7;
  const int cL = cl ? cl - 1 : 0, cR = (cl < 127) ? cl + 1 : 127;
  short8 tC[8];
  #pragma unroll
  for (int j = 0; j < 8; ++j) {
    const int R = rb * 64 + j * 8;
    short8 sL = *(const short8*)(fsm + cL * 256 + (R ^ ((cL & 31) << 3)));
    short8 sC = *(const short8*)(fsm + cl * 256 + (R ^ ((cl & 31) << 3)));
    short8 sR = *(const short8*)(fsm + cR * 256 + (R ^ ((cR & 31) << 3)));
    short8 o;
    #pragma unroll
    for (int k = 0; k < 8; ++k) {
      float a = bf2f((u16)sL[k]), b = bf2f((u16)sC[k]), c = bf2f((u16)sR[k]);
      float v = fmaxf(fmaf(w10, a, fmaf(w11, b, fmaf(w12, c, c1b))), 0.0f);
      o[k] = (short)f2bf(v);
    }
    *(short8*)(tsm + cl * 256 + (R ^ ((cl & 31) << 3))) = o;
    tC[j] = o;
  }
  __syncthreads();

  // ---- E3: out = conv2(tmp), store interior cols 2..125 ----
  const bool wr_ok = (cl >= 2 && cl <= 125);
  #pragma unroll
  for (int j = 0; j < 8; ++j) {
    const int R = rb * 64 + j * 8;
    short8 tL = *(const short8*)(tsm + cL * 256 + (R ^ ((cL & 31) << 3)));
    short8 tR = *(const short8*)(tsm + cR * 256 + (R ^ ((cR & 31) << 3)));
    #pragma unroll
    for (int k = 0; k < 8; ++k) {
      float v = fmaf(w20, bf2f((u16)tL[k]),
                fmaf(w21, bf2f((u16)tC[j][k]),
                fmaf(w22, bf2f((u16)tR[k]), c2b)));
      if (wr_ok)
        out[(size_t)(brow + R + k) * Dn + bx * 128 + cl] = v;
    }
  }
}

// ------- kernel 4: seam cleanup — out cols {E0,E0+1,E0+126,E0+127} ---------
// Zero-pad semantics: conv2's pad gives tmp(-1)=tmp(768)=0 (NOT conv1 of
// zeros); conv1's pad gives fused(-1)=fused(768)=0 inside tmp(0)/tmp(767).
__global__ __launch_bounds__(256) void seam_k(const u16* __restrict__ seam,
                                              float* __restrict__ out,
                                              const float* __restrict__ cw1,
                                              const float* __restrict__ cb1,
                                              const float* __restrict__ cw2,
                                              const float* __restrict__ cb2) {
  const int bid = blockIdx.x;          // by*6+bx
  const int by = bid / 6, bx = bid - by * 6;
  const int r = threadIdx.x;
  const float w10 = cw1[0], w11 = cw1[1], w12 = cw1[2], c1b = cb1[0];
  const float w20 = cw2[0], w21 = cw2[1], w22 = cw2[2], c2b = cb2[0];
  #define SM(B, I) bf2f(seam[((size_t)(B) * 8 + (I)) * 256 + r])
  float fm2 = 0.f, fm1 = 0.f, fR0 = 0.f, fR1 = 0.f;
  if (bx > 0) { fm2 = SM(bid - 1, 6); fm1 = SM(bid - 1, 7); }
  if (bx < 5) { fR0 = SM(bid + 1, 0); fR1 = SM(bid + 1, 1); }
  const float f0 = SM(bid, 0), f1 = SM(bid, 1), f2 = SM(bid, 2), f3 = SM(bid, 3);
  const float f124 = SM(bid, 4), f125 = SM(bid, 5), f126 = SM(bid, 6), f127 = SM(bid, 7);
  #undef SM
  #define C1(a, b, c) fmaxf(fmaf(w10, (a), fmaf(w11, (b), fmaf(w12, (c), c1b))), 0.0f)
  const float tm1  = (bx > 0) ? C1(fm2, fm1, f0) : 0.0f;   // tmp(-1)=0 at edge
  const float t0   = C1(fm1, f0, f1);
  const float t1   = C1(f0, f1, f2);
  const float t2   = C1(f1, f2, f3);
  const float t125 = C1(f124, f125, f126);
  const float t126 = C1(f125, f126, f127);
  const float t127 = C1(f126, f127, fR0);
  const float t128 = (bx < 5) ? C1(f127, fR0, fR1) : 0.0f;  // tmp(768)=0 at edge
  #undef C1
  const size_t go = (size_t)(by * 256 + r) * Dn + bx * 128;
  out[go + 0]   = fmaf(w20, tm1,  fmaf(w21, t0,   fmaf(w22, t1,   c2b)));
  out[go + 1]   = fmaf(w20, t0,   fmaf(w21, t1,   fmaf(w22, t2,   c2b)));
  out[go + 126] = fmaf(w20, t125, fmaf(w21, t126, fmaf(w22, t127, c2b)));
  out[go + 127] = fmaf(w20, t126, fmaf(w21, t127, fmaf(w22, t128, c2b)));
}

extern "C" void kernel_launch(void* const* d_in, const int* in_sizes, int n_in,
                              void* d_out, int out_size, void* d_ws, size_t ws_size,
                              hipStream_t stream) {
  const float* text = (const float*)d_in[0];
  const float* vf   = (const float*)d_in[1];
  const float* W1   = (const float*)d_in[2];
  const float* b1   = (const float*)d_in[3];
  const float* W2   = (const float*)d_in[4];
  const float* b2   = (const float*)d_in[5];
  const float* cw1  = (const float*)d_in[6];
  const float* cb1  = (const float*)d_in[7];
  const float* cw2  = (const float*)d_in[8];
  const float* cb2  = (const float*)d_in[9];
  float* out = (float*)d_out;

  u16* X    = (u16*)d_ws;                                  // [81920][768] bf16
  u16* Wt   = X + (size_t)Mn * Dn;                         // [1536][768] bf16
  u16* seam = Wt + (size_t)Nn * Dn;                        // [320*6][8][256] bf16

  softmax_k<<<Mn, 192, 0, stream>>>(vf, X);
  build_wt_k<<<(Dn * Dn + 255) / 256, 256, 0, stream>>>(W1, W2, Wt);
  gemm_fuse_k<<<GRID, 512, 0, stream>>>(X, Wt, b1, b2, text, out, seam,
                                        cw1, cb1, cw2, cb2);
  seam_k<<<GRID, 256, 0, stream>>>(seam, out, cw1, cb1, cw2, cb2);
}

// Round 16
// 346.634 us; speedup vs baseline: 1.7529x; 1.0761x over previous
//
#include <hip/hip_runtime.h>

typedef unsigned short u16;
typedef unsigned char u8;
typedef __attribute__((ext_vector_type(8))) short short8;
typedef __attribute__((ext_vector_type(4))) float f32x4;

#define Bn 4096
#define Vn 20
#define Dn 768
#define Mn (Bn * Vn)   // 81920 rows
#define Nn (2 * Dn)    // 1536 packed m1/m2 columns

#define BM 256
#define BNt 256            // Wt rows per block tile (= 128 output e-columns)
#define NTILES (Nn / BNt)  // 6 N-tiles
#define GRID ((Mn / BM) * NTILES)   // 320 * 6 = 1920, %8 == 0

#define SCL 32.0f          // fp8 pre-scale for X and W
#define ISCL2 (1.0f / 1024.0f)

typedef __attribute__((address_space(1))) void GV;
typedef __attribute__((address_space(3))) void LV;

__device__ __forceinline__ u16 f2bf(float f) {
  union { float f; unsigned u; } v; v.f = f;
  unsigned r = v.u + 0x7FFFu + ((v.u >> 16) & 1u);  // round-to-nearest-even
  return (u16)(r >> 16);
}
__device__ __forceinline__ float bf2f(u16 x) {
  union { unsigned u; float f; } v; v.u = ((unsigned)x) << 16; return v.f;
}

// fp8 LDS map within a 256x32 (rows x K-bytes) region (8192 B):
//   byte(r, b) = (r>>2)*128 + (r&3)*32 + ((c16 ^ ((r>>2)&1))<<4) + (b&15),
//   c16 = b>>4. b64 reads: 2-way bank aliasing only (free, m136); 16B-chunk
//   preserving so gload_lds staging stays one contiguous 16B load/thread.
__device__ __forceinline__ int lds8(int r, int hi) {
  return (r >> 2) * 128 + (r & 3) * 32 + ((((hi >> 1) ^ ((r >> 2) & 1))) << 4)
         + (hi & 1) * 8;
}

// ---------------- kernel 1: row softmax -> fp8 X (x32 scale) ----------------
__global__ __launch_bounds__(192) void softmax_k(const float* __restrict__ vf,
                                                 u8* __restrict__ X8) {
  size_t row = blockIdx.x;
  const float4* p = (const float4*)(vf + row * Dn);
  int t = threadIdx.x;
  float4 v = p[t];
  float mx = fmaxf(fmaxf(v.x, v.y), fmaxf(v.z, v.w));
  #pragma unroll
  for (int off = 32; off; off >>= 1) mx = fmaxf(mx, __shfl_xor(mx, off));
  __shared__ float rr[3];
  __shared__ float rs[3];
  int wv = t >> 6, ln = t & 63;
  if (!ln) rr[wv] = mx;
  __syncthreads();
  mx = fmaxf(fmaxf(rr[0], rr[1]), rr[2]);
  float e0 = __expf(v.x - mx), e1 = __expf(v.y - mx);
  float e2 = __expf(v.z - mx), e3 = __expf(v.w - mx);
  float s = e0 + e1 + e2 + e3;
  #pragma unroll
  for (int off = 32; off; off >>= 1) s += __shfl_xor(s, off);
  if (!ln) rs[wv] = s;
  __syncthreads();
  float inv = SCL / (rs[0] + rs[1] + rs[2]);
  unsigned pk = 0;
  pk = __builtin_amdgcn_cvt_pk_fp8_f32(e0 * inv, e1 * inv, pk, false);
  pk = __builtin_amdgcn_cvt_pk_fp8_f32(e2 * inv, e3 * inv, pk, true);
  ((unsigned*)(X8 + row * Dn))[t] = pk;
}

// ---- kernel 2: pack W1/W2 block-of-32 interleaved, fp8 x32 [1536][768] -----
__global__ __launch_bounds__(256) void build_wt_k(const float* __restrict__ W1,
                                                  const float* __restrict__ W2,
                                                  u8* __restrict__ Wt8) {
  int idx = blockIdx.x * 256 + threadIdx.x;        // over 768 * 192
  if (idx >= Dn * (Dn / 4)) return;
  int j = idx / (Dn / 4), d4 = (idx - j * (Dn / 4)) * 4;
  int b = j >> 5, c = j & 31;
  float4 a = *(const float4*)(W1 + (size_t)j * Dn + d4);
  float4 e = *(const float4*)(W2 + (size_t)j * Dn + d4);
  unsigned p1 = 0, p2 = 0;
  p1 = __builtin_amdgcn_cvt_pk_fp8_f32(a.x * SCL, a.y * SCL, p1, false);
  p1 = __builtin_amdgcn_cvt_pk_fp8_f32(a.z * SCL, a.w * SCL, p1, true);
  p2 = __builtin_amdgcn_cvt_pk_fp8_f32(e.x * SCL, e.y * SCL, p2, false);
  p2 = __builtin_amdgcn_cvt_pk_fp8_f32(e.z * SCL, e.w * SCL, p2, true);
  *(unsigned*)(Wt8 + (size_t)(b * 64 + c) * Dn + d4)      = p1;
  *(unsigned*)(Wt8 + (size_t)(b * 64 + 32 + c) * Dn + d4) = p2;
}

// -------- kernel 3: fp8 GEMM (R15 8-phase host) + FUSED CONV epilogue -------
// Identical schedule/barrier/ledger structure to the verified R15 kernel;
// fp8 halves LDS bytes: ds_read_b64 frags, 1 gload/region staging.
// Ledger: prologue 8 loads -> vmcnt(6) confirms T0Kh0; steady state 1 load
// per staging phase, vmcnt(2) at P2/P4/P6/P8 = "newest 2 phases in flight";
// i==5 P6 drains vmcnt(0) for the epilogue LDS reuse.
__global__ __launch_bounds__(512, 2) void gemm_fuse_k(
    const u8* __restrict__ X8, const u8* __restrict__ Wt8,
    const float* __restrict__ b1, const float* __restrict__ b2,
    const float* __restrict__ text, float* __restrict__ out,
    u16* __restrict__ seam,
    const float* __restrict__ cw1, const float* __restrict__ cb1,
    const float* __restrict__ cw2, const float* __restrict__ cb2) {
  __shared__ __align__(16) u16 smem[65536];   // 128 KiB (K-loop uses 64 KiB)
  u8* smem8 = (u8*)smem;

  const int h = blockIdx.x;                      // GRID = 1920 blocks, %8==0
  const int lin = (h & 7) * (GRID / 8) + (h >> 3);
  const int by = lin / NTILES, bx = lin - by * NTILES;
  const int brow = by * BM;

  const int t = threadIdx.x, w = t >> 6, l = t & 63;
  const int lo = l & 15, hi = l >> 4;
  const int wrr = w >> 2, wcc = w & 3;

  int offA[8], offB[4];
  #pragma unroll
  for (int m = 0; m < 8; ++m) offA[m] = lds8(wrr * 128 + m * 16 + lo, hi);
  #pragma unroll
  for (int n = 0; n < 4; ++n) offB[n] = lds8(wcc * 64 + n * 16 + lo, hi);

  // staging source: thread t fills LDS bytes [t*16, t*16+16) of a region
  const u8* gA;
  const u8* gB;
  {
    int r = (t >> 3) * 4 + ((t & 7) >> 1);
    int c16 = (t & 1) ^ ((t >> 3) & 1);
    gA = X8 + (size_t)(brow + r) * Dn + c16 * 16;
    gB = Wt8 + (size_t)(bx * BNt + r) * Dn + c16 * 16;
  }

#define STG_A(DST, KOFF) __builtin_amdgcn_global_load_lds( \
    (GV*)(gA + (KOFF)), (LV*)(smem8 + (DST) + w * 1024), 16, 0, 0)
#define STG_B(DST, KOFF) __builtin_amdgcn_global_load_lds( \
    (GV*)(gB + (KOFF)), (LV*)(smem8 + (DST) + w * 1024), 16, 0, 0)

  // prologue: T0Kh0, T1Kh0, T0Kh1, T1Kh1 (8 loads)
  STG_A(0, 0);              STG_B(16384, 0);          // T0 Kh0 -> slot0
  STG_A(32768, 64);         STG_B(49152, 64);         // T1 Kh0 -> slot1
  STG_A(8192, 32);          STG_B(24576, 32);         // T0 Kh1
  STG_A(40960, 96);         STG_B(57344, 96);         // T1 Kh1
  asm volatile("s_waitcnt vmcnt(6)" ::: "memory");    // T0-Kh0 resident
  __builtin_amdgcn_s_barrier();

  f32x4 acc[8][4] = {};
  long af[8], bb0, bb1;

#define PH(SB, KH, NH, NEWA, STG, VM) do {                                     \
    if (NEWA) { _Pragma("unroll") for (int m = 0; m < 8; ++m)                  \
      af[m] = *(const long*)(smem8 + (SB) + (KH) * 8192 + offA[m]); }          \
    bb0 = *(const long*)(smem8 + (SB) + 16384 + (KH) * 8192 + offB[(NH)*2]);   \
    bb1 = *(const long*)(smem8 + (SB) + 16384 + (KH) * 8192 + offB[(NH)*2+1]); \
    STG;                                                                       \
    __builtin_amdgcn_s_barrier();                                              \
    asm volatile("s_waitcnt lgkmcnt(0)" ::: "memory");                         \
    __builtin_amdgcn_sched_barrier(0);                                         \
    __builtin_amdgcn_s_setprio(1);                                             \
    _Pragma("unroll") for (int m = 0; m < 8; ++m) {                            \
      acc[m][(NH)*2]   = __builtin_amdgcn_mfma_f32_16x16x32_fp8_fp8(af[m], bb0, acc[m][(NH)*2],   0, 0, 0); \
      acc[m][(NH)*2+1] = __builtin_amdgcn_mfma_f32_16x16x32_fp8_fp8(af[m], bb1, acc[m][(NH)*2+1], 0, 0, 0); \
    }                                                                          \
    __builtin_amdgcn_s_setprio(0);                                             \
    VM;                                                                        \
    __builtin_amdgcn_s_barrier();                                              \
  } while (0)

#define VM2 asm volatile("s_waitcnt vmcnt(2)" ::: "memory")
#define VM0 asm volatile("s_waitcnt vmcnt(0)" ::: "memory")

  #pragma unroll
  for (int i = 0; i < 6; ++i) {
    const int ka = (2 * i + 1) * 64;
    const int kb = (2 * i + 2) * 64;
    PH(0, 0, 0, true,  if (i >= 1) STG_A(32768, ka),      ;  );
    PH(0, 0, 1, false, if (i >= 1) STG_B(49152, ka),      VM2);
    PH(0, 1, 0, true,  if (i >= 1) STG_A(40960, ka + 32), ;  );
    PH(0, 1, 1, false, if (i >= 1) STG_B(57344, ka + 32), VM2);
    PH(32768, 0, 0, true,  if (i <= 4) STG_A(0, kb),          ;  );
    PH(32768, 0, 1, false, if (i <= 4) STG_B(16384, kb),      if (i == 5) { VM0; } else { VM2; });
    PH(32768, 1, 0, true,  if (i <= 4) STG_A(8192, kb + 32),  ;  );
    PH(32768, 1, 1, false, if (i <= 4) STG_B(24576, kb + 32), if (i <= 4) { VM2; });
  }
#undef PH
#undef VM2
#undef VM0
#undef STG_A
#undef STG_B

  // ======================= fused-conv epilogue ==============================
  // vmcnt==0 here (i=5 P6 drained; P7/P8 stage nothing) -> smem reusable.
  const float w10 = cw1[0], w11 = cw1[1], w12 = cw1[2], c1b = cb1[0];
  const float w20 = cw2[0], w21 = cw2[1], w22 = cw2[2], c2b = cb2[0];

  u16* fsm = smem;           // fused [c][r]: idx = c*256 + (r ^ ((c&31)<<3))
  u16* tsm = smem + 32768;   // tmp, same layout

  // ---- E1: fused -> LDS bf16 (+ seam store for cols 0-3,124-127) ----
  #pragma unroll
  for (int n = 0; n < 2; ++n) {
    const int cl = wcc * 32 + n * 16 + lo;       // local col 0..127
    const int e  = bx * 128 + cl;
    const float B1 = b1[e], B2 = b2[e];
    #pragma unroll
    for (int m = 0; m < 8; ++m) {
      const int rl = wrr * 128 + m * 16 + hi * 4;
      uint2 pk;
      u16* pku = (u16*)&pk;
      #pragma unroll
      for (int r = 0; r < 4; ++r) {
        const int gr = brow + rl + r;
        const float v1 = acc[m][n][r] * ISCL2 + B1;
        const float v2 = acc[m][n + 2][r] * ISCL2 + B2;
        const float tf = text[(size_t)(gr / Vn) * Dn + e];
        pku[r] = f2bf(fmaxf(tf * v1 + v2, 0.0f));
      }
      *(uint2*)(fsm + cl * 256 + (rl ^ ((cl & 31) << 3))) = pk;
      const int sidx = (cl < 4) ? cl : ((cl >= 124) ? cl - 120 : -1);
      if (sidx >= 0)
        *(uint2*)(seam + ((size_t)(by * 6 + bx) * 8 + sidx) * 256 + rl) = pk;
    }
  }
  __syncthreads();

  // ---- E2: tmp = relu(conv1(fused)), per-thread col; own col kept in regs --
  const int cl = t & 127, rb = t >> 7;
  const int cL = cl ? cl - 1 : 0, cR = (cl < 127) ? cl + 1 : 127;
  short8 tC[8];
  #pragma unroll
  for (int j = 0; j < 8; ++j) {
    const int R = rb * 64 + j * 8;
    short8 sL = *(const short8*)(fsm + cL * 256 + (R ^ ((cL & 31) << 3)));
    short8 sC = *(const short8*)(fsm + cl * 256 + (R ^ ((cl & 31) << 3)));
    short8 sR = *(const short8*)(fsm + cR * 256 + (R ^ ((cR & 31) << 3)));
    short8 o;
    #pragma unroll
    for (int k = 0; k < 8; ++k) {
      float a = bf2f((u16)sL[k]), b = bf2f((u16)sC[k]), c = bf2f((u16)sR[k]);
      float v = fmaxf(fmaf(w10, a, fmaf(w11, b, fmaf(w12, c, c1b))), 0.0f);
      o[k] = (short)f2bf(v);
    }
    *(short8*)(tsm + cl * 256 + (R ^ ((cl & 31) << 3))) = o;
    tC[j] = o;
  }
  __syncthreads();

  // ---- E3: out = conv2(tmp), store interior cols 2..125 ----
  const bool wr_ok = (cl >= 2 && cl <= 125);
  #pragma unroll
  for (int j = 0; j < 8; ++j) {
    const int R = rb * 64 + j * 8;
    short8 tL = *(const short8*)(tsm + cL * 256 + (R ^ ((cL & 31) << 3)));
    short8 tR = *(const short8*)(tsm + cR * 256 + (R ^ ((cR & 31) << 3)));
    #pragma unroll
    for (int k = 0; k < 8; ++k) {
      float v = fmaf(w20, bf2f((u16)tL[k]),
                fmaf(w21, bf2f((u16)tC[j][k]),
                fmaf(w22, bf2f((u16)tR[k]), c2b)));
      if (wr_ok)
        out[(size_t)(brow + R + k) * Dn + bx * 128 + cl] = v;
    }
  }
}

// ------- kernel 4: seam cleanup — out cols {E0,E0+1,E0+126,E0+127} ---------
// Zero-pad semantics: conv2's pad gives tmp(-1)=tmp(768)=0 (NOT conv1 of
// zeros); conv1's pad gives fused(-1)=fused(768)=0 inside tmp(0)/tmp(767).
__global__ __launch_bounds__(256) void seam_k(const u16* __restrict__ seam,
                                              float* __restrict__ out,
                                              const float* __restrict__ cw1,
                                              const float* __restrict__ cb1,
                                              const float* __restrict__ cw2,
                                              const float* __restrict__ cb2) {
  const int bid = blockIdx.x;          // by*6+bx
  const int by = bid / 6, bx = bid - by * 6;
  const int r = threadIdx.x;
  const float w10 = cw1[0], w11 = cw1[1], w12 = cw1[2], c1b = cb1[0];
  const float w20 = cw2[0], w21 = cw2[1], w22 = cw2[2], c2b = cb2[0];
  #define SM(B, I) bf2f(seam[((size_t)(B) * 8 + (I)) * 256 + r])
  float fm2 = 0.f, fm1 = 0.f, fR0 = 0.f, fR1 = 0.f;
  if (bx > 0) { fm2 = SM(bid - 1, 6); fm1 = SM(bid - 1, 7); }
  if (bx < 5) { fR0 = SM(bid + 1, 0); fR1 = SM(bid + 1, 1); }
  const float f0 = SM(bid, 0), f1 = SM(bid, 1), f2 = SM(bid, 2), f3 = SM(bid, 3);
  const float f124 = SM(bid, 4), f125 = SM(bid, 5), f126 = SM(bid, 6), f127 = SM(bid, 7);
  #undef SM
  #define C1(a, b, c) fmaxf(fmaf(w10, (a), fmaf(w11, (b), fmaf(w12, (c), c1b))), 0.0f)
  const float tm1  = (bx > 0) ? C1(fm2, fm1, f0) : 0.0f;   // tmp(-1)=0 at edge
  const float t0   = C1(fm1, f0, f1);
  const float t1   = C1(f0, f1, f2);
  const float t2   = C1(f1, f2, f3);
  const float t125 = C1(f124, f125, f126);
  const float t126 = C1(f125, f126, f127);
  const float t127 = C1(f126, f127, fR0);
  const float t128 = (bx < 5) ? C1(f127, fR0, fR1) : 0.0f;  // tmp(768)=0 at edge
  #undef C1
  const size_t go = (size_t)(by * 256 + r) * Dn + bx * 128;
  out[go + 0]   = fmaf(w20, tm1,  fmaf(w21, t0,   fmaf(w22, t1,   c2b)));
  out[go + 1]   = fmaf(w20, t0,   fmaf(w21, t1,   fmaf(w22, t2,   c2b)));
  out[go + 126] = fmaf(w20, t125, fmaf(w21, t126, fmaf(w22, t127, c2b)));
  out[go + 127] = fmaf(w20, t126, fmaf(w21, t127, fmaf(w22, t128, c2b)));
}

extern "C" void kernel_launch(void* const* d_in, const int* in_sizes, int n_in,
                              void* d_out, int out_size, void* d_ws, size_t ws_size,
                              hipStream_t stream) {
  const float* text = (const float*)d_in[0];
  const float* vf   = (const float*)d_in[1];
  const float* W1   = (const float*)d_in[2];
  const float* b1   = (const float*)d_in[3];
  const float* W2   = (const float*)d_in[4];
  const float* b2   = (const float*)d_in[5];
  const float* cw1  = (const float*)d_in[6];
  const float* cb1  = (const float*)d_in[7];
  const float* cw2  = (const float*)d_in[8];
  const float* cb2  = (const float*)d_in[9];
  float* out = (float*)d_out;

  u8*  X8   = (u8*)d_ws;                                   // [81920][768] fp8
  u8*  Wt8  = X8 + (size_t)Mn * Dn;                        // [1536][768] fp8
  u16* seam = (u16*)(Wt8 + (size_t)Nn * Dn);               // [1920][8][256] bf16

  softmax_k<<<Mn, 192, 0, stream>>>(vf, X8);
  build_wt_k<<<(Dn * (Dn / 4) + 255) / 256, 256, 0, stream>>>(W1, W2, Wt8);
  gemm_fuse_k<<<GRID, 512, 0, stream>>>(X8, Wt8, b1, b2, text, out, seam,
                                        cw1, cb1, cw2, cb2);
  seam_k<<<GRID, 256, 0, stream>>>(seam, out, cw1, cb1, cw2, cb2);
}